// Round 1
// baseline (592.680 us; speedup 1.0000x reference)
//
#include <hip/hip_runtime.h>

#define NN 50000
#define NE 500000
#define FIN 16
#define FOUT 16
#define HID 64

// ---------------------------------------------------------------------------
// One edge per lane. All weight reads (W1,b1,W2,b2) are wave-uniform ->
// scalar loads on the scalar pipe. Per-lane per-edge FMA count ~= 18.7k,
// exactly the algorithmic FLOPs (layer1 fused into j-loop, computed once).
// ---------------------------------------------------------------------------
__global__ __launch_bounds__(256) void dgc_edge(
    const float* __restrict__ x, const float* __restrict__ ef,
    const int* __restrict__ src, const int* __restrict__ dst,
    const float* __restrict__ W1, const float* __restrict__ b1,
    const float* __restrict__ W2, const float* __restrict__ b2,
    float* __restrict__ msum, float* __restrict__ cnt)
{
    const int e = blockIdx.x * blockDim.x + threadIdx.x;
    if (e >= NE) return;

    // edge features (16 floats, 4x float4, coalesced in 64B rows)
    float efv[16];
    {
        const float4* p = reinterpret_cast<const float4*>(ef) + (size_t)e * 4;
        float4 a = p[0], b = p[1], c = p[2], d = p[3];
        efv[0]=a.x; efv[1]=a.y; efv[2]=a.z;  efv[3]=a.w;
        efv[4]=b.x; efv[5]=b.y; efv[6]=b.z;  efv[7]=b.w;
        efv[8]=c.x; efv[9]=c.y; efv[10]=c.z; efv[11]=c.w;
        efv[12]=d.x; efv[13]=d.y; efv[14]=d.z; efv[15]=d.w;
    }

    // gathered source node features (random row, L2/L3 resident: x is 3.2MB)
    const int s = src[e];
    float xs[16];
    {
        const float4* p = reinterpret_cast<const float4*>(x) + (size_t)s * 4;
        float4 a = p[0], b = p[1], c = p[2], d = p[3];
        xs[0]=a.x; xs[1]=a.y; xs[2]=a.z;  xs[3]=a.w;
        xs[4]=b.x; xs[5]=b.y; xs[6]=b.z;  xs[7]=b.w;
        xs[8]=c.x; xs[9]=c.y; xs[10]=c.z; xs[11]=c.w;
        xs[12]=d.x; xs[13]=d.y; xs[14]=d.z; xs[15]=d.w;
    }

    // msg[o] = sum_i xs[i]*b2[i*16+o]  (the +b2 part of W)
    float msg[16];
    #pragma unroll
    for (int o = 0; o < 16; ++o) msg[o] = 0.f;
    #pragma unroll
    for (int i = 0; i < 16; ++i) {
        const float xi = xs[i];
        #pragma unroll
        for (int o = 0; o < 16; ++o)
            msg[o] = fmaf(xi, b2[i * 16 + o], msg[o]);
    }

    // main loop over hidden units: msg[o] += h_j * (sum_i xs[i]*W2[j, i*16+o])
    // j is wave-uniform; W1/W2 reads become s_load. Kept rolled (I-cache).
    for (int j = 0; j < HID; ++j) {
        float hj = b1[j];
        #pragma unroll
        for (int i = 0; i < 16; ++i)
            hj = fmaf(efv[i], W1[i * HID + j], hj);
        hj = fmaxf(hj, 0.f);

        const float* __restrict__ w2r = W2 + (size_t)j * 256;
        float t[16];
        #pragma unroll
        for (int o = 0; o < 16; ++o) t[o] = 0.f;
        #pragma unroll
        for (int i = 0; i < 16; ++i) {
            const float xi = xs[i];
            #pragma unroll
            for (int o = 0; o < 16; ++o)
                t[o] = fmaf(xi, w2r[i * 16 + o], t[o]);
        }
        #pragma unroll
        for (int o = 0; o < 16; ++o)
            msg[o] = fmaf(hj, t[o], msg[o]);
    }

    // scatter-add into accumulators
    const int d = dst[e];
    float* mrow = msum + (size_t)d * 16;
    #pragma unroll
    for (int o = 0; o < 16; ++o) atomicAdd(mrow + o, msg[o]);
    atomicAdd(cnt + d, 1.0f);
}

// out[n,o] = (cnt[n]>0 ? msum[n,o]/cnt[n] : x[n,o]) + bias[o]
__global__ __launch_bounds__(256) void dgc_finalize(
    const float* __restrict__ msum, const float* __restrict__ cnt,
    const float* __restrict__ x, const float* __restrict__ bias,
    float* __restrict__ out)
{
    const int t = blockIdx.x * blockDim.x + threadIdx.x;
    if (t >= NN * FOUT) return;
    const int n = t >> 4;
    const int o = t & 15;
    const float c = cnt[n];
    const float v = (c > 0.f) ? (msum[t] / c) : x[t];
    out[t] = v + bias[o];
}

extern "C" void kernel_launch(void* const* d_in, const int* in_sizes, int n_in,
                              void* d_out, int out_size, void* d_ws, size_t ws_size,
                              hipStream_t stream) {
    const float* x    = (const float*)d_in[0];
    const float* ef   = (const float*)d_in[1];
    const int*   src  = (const int*)d_in[2];
    const int*   dst  = (const int*)d_in[3];
    const float* W1   = (const float*)d_in[4];
    const float* b1   = (const float*)d_in[5];
    const float* W2   = (const float*)d_in[6];
    const float* b2   = (const float*)d_in[7];
    const float* bias = (const float*)d_in[8];
    float* out = (float*)d_out;

    float* msum = (float*)d_ws;                 // NN*16 floats
    float* cnt  = msum + (size_t)NN * FOUT;     // NN floats

    hipMemsetAsync(d_ws, 0, ((size_t)NN * FOUT + NN) * sizeof(float), stream);

    dgc_edge<<<(NE + 255) / 256, 256, 0, stream>>>(x, ef, src, dst, W1, b1, W2, b2,
                                                   msum, cnt);

    const int nout = NN * FOUT;
    dgc_finalize<<<(nout + 255) / 256, 256, 0, stream>>>(msum, cnt, x, bias, out);
}

// Round 2
// 333.760 us; speedup vs baseline: 1.7758x; 1.7758x over previous
//
#include <hip/hip_runtime.h>

#define NN 50000
#define NE 500000
#define FIN 16
#define FOUT 16
#define HID 64

// ---------------------------------------------------------------------------
// Phase 1: per-edge MLP + message compute. One edge per lane; weight reads are
// wave-uniform -> scalar loads. Writes msg row (64B, coalesced float4) and does
// ONE atomic (degree count, also yields CSR rank). Round-1 lesson: 17 atomics/
// edge write-through past L2 (265MB) and serialize at ~6 atomics/cy chip-wide.
// ---------------------------------------------------------------------------
__global__ __launch_bounds__(256) void dgc_edge_csr(
    const float* __restrict__ x, const float* __restrict__ ef,
    const int* __restrict__ src, const int* __restrict__ dst,
    const float* __restrict__ W1, const float* __restrict__ b1,
    const float* __restrict__ W2, const float* __restrict__ b2,
    float* __restrict__ msg, int* __restrict__ pos, int* __restrict__ deg)
{
    const int e = blockIdx.x * blockDim.x + threadIdx.x;
    if (e >= NE) return;

    float efv[16];
    {
        const float4* p = reinterpret_cast<const float4*>(ef) + (size_t)e * 4;
        float4 a = p[0], b = p[1], c = p[2], d = p[3];
        efv[0]=a.x; efv[1]=a.y; efv[2]=a.z;  efv[3]=a.w;
        efv[4]=b.x; efv[5]=b.y; efv[6]=b.z;  efv[7]=b.w;
        efv[8]=c.x; efv[9]=c.y; efv[10]=c.z; efv[11]=c.w;
        efv[12]=d.x; efv[13]=d.y; efv[14]=d.z; efv[15]=d.w;
    }

    const int s = src[e];
    float xs[16];
    {
        const float4* p = reinterpret_cast<const float4*>(x) + (size_t)s * 4;
        float4 a = p[0], b = p[1], c = p[2], d = p[3];
        xs[0]=a.x; xs[1]=a.y; xs[2]=a.z;  xs[3]=a.w;
        xs[4]=b.x; xs[5]=b.y; xs[6]=b.z;  xs[7]=b.w;
        xs[8]=c.x; xs[9]=c.y; xs[10]=c.z; xs[11]=c.w;
        xs[12]=d.x; xs[13]=d.y; xs[14]=d.z; xs[15]=d.w;
    }

    // msg[o] = sum_i xs[i]*b2[i*16+o]
    float m[16];
    #pragma unroll
    for (int o = 0; o < 16; ++o) m[o] = 0.f;
    #pragma unroll
    for (int i = 0; i < 16; ++i) {
        const float xi = xs[i];
        #pragma unroll
        for (int o = 0; o < 16; ++o)
            m[o] = fmaf(xi, b2[i * 16 + o], m[o]);
    }

    // msg[o] += h_j * (sum_i xs[i]*W2[j, i*16+o]); j wave-uniform -> s_load
    for (int j = 0; j < HID; ++j) {
        float hj = b1[j];
        #pragma unroll
        for (int i = 0; i < 16; ++i)
            hj = fmaf(efv[i], W1[i * HID + j], hj);
        hj = fmaxf(hj, 0.f);

        const float* __restrict__ w2r = W2 + (size_t)j * 256;
        float t[16];
        #pragma unroll
        for (int o = 0; o < 16; ++o) t[o] = 0.f;
        #pragma unroll
        for (int i = 0; i < 16; ++i) {
            const float xi = xs[i];
            #pragma unroll
            for (int o = 0; o < 16; ++o)
                t[o] = fmaf(xi, w2r[i * 16 + o], t[o]);
        }
        #pragma unroll
        for (int o = 0; o < 16; ++o)
            m[o] = fmaf(hj, t[o], m[o]);
    }

    // coalesced 64B row store
    float4* mr = reinterpret_cast<float4*>(msg + (size_t)e * 16);
    mr[0] = make_float4(m[0], m[1], m[2], m[3]);
    mr[1] = make_float4(m[4], m[5], m[6], m[7]);
    mr[2] = make_float4(m[8], m[9], m[10], m[11]);
    mr[3] = make_float4(m[12], m[13], m[14], m[15]);

    pos[e] = atomicAdd(deg + dst[e], 1);   // the ONLY atomic
}

// ---------------------------------------------------------------------------
// Phase 2: exclusive scan of deg[NN] -> offs[NN+1]. Single workgroup, 1024 thr.
// ---------------------------------------------------------------------------
__global__ __launch_bounds__(1024) void dgc_scan(
    const int* __restrict__ deg, int* __restrict__ offs)
{
    __shared__ int wsum[16];
    const int tid = threadIdx.x;
    const int lane = tid & 63;
    const int wid = tid >> 6;
    int carry = 0;

    for (int base = 0; base < NN; base += 1024) {
        const int idx = base + tid;
        const int v = (idx < NN) ? deg[idx] : 0;
        // inclusive wave scan
        int s = v;
        #pragma unroll
        for (int d = 1; d < 64; d <<= 1) {
            int t = __shfl_up(s, d, 64);
            if (lane >= d) s += t;
        }
        if (lane == 63) wsum[wid] = s;
        __syncthreads();
        if (wid == 0 && lane < 16) {
            int w = wsum[lane];
            #pragma unroll
            for (int d = 1; d < 16; d <<= 1) {
                int t = __shfl_up(w, d, 64);
                if (lane >= d) w += t;
            }
            wsum[lane] = w;
        }
        __syncthreads();
        const int wpre = (wid == 0) ? 0 : wsum[wid - 1];
        if (idx < NN) offs[idx] = carry + wpre + (s - v);   // exclusive
        carry += wsum[15];
        __syncthreads();
    }
    if (tid == 0) offs[NN] = carry;   // == NE
}

// ---------------------------------------------------------------------------
// Phase 3: scatter edge ids into CSR order.
// ---------------------------------------------------------------------------
__global__ __launch_bounds__(256) void dgc_scatter(
    const int* __restrict__ dst, const int* __restrict__ pos,
    const int* __restrict__ offs, int* __restrict__ eidx)
{
    const int e = blockIdx.x * blockDim.x + threadIdx.x;
    if (e >= NE) return;
    eidx[offs[dst[e]] + pos[e]] = e;
}

// ---------------------------------------------------------------------------
// Phase 4: per-node gather-mean. 16 lanes per node (lane o); eidx broadcast,
// msg row read is one 64B transaction per edge (each row read exactly once).
// ---------------------------------------------------------------------------
__global__ __launch_bounds__(256) void dgc_gather(
    const float* __restrict__ msg, const int* __restrict__ offs,
    const int* __restrict__ eidx, const float* __restrict__ x,
    const float* __restrict__ bias, float* __restrict__ out)
{
    const int t = blockIdx.x * blockDim.x + threadIdx.x;
    if (t >= NN * FOUT) return;
    const int n = t >> 4;
    const int o = t & 15;
    const int beg = offs[n], end = offs[n + 1];
    float s = 0.f;
    for (int k = beg; k < end; ++k) {
        const int e = eidx[k];
        s += msg[(size_t)e * 16 + o];
    }
    const int d = end - beg;
    const float v = (d > 0) ? (s / (float)d) : x[t];
    out[t] = v + bias[o];
}

// ---------------------------------------------------------------------------
// Fallback (round-1 proven path) if ws_size is too small for CSR buffers.
// ---------------------------------------------------------------------------
__global__ __launch_bounds__(256) void dgc_edge_atomic(
    const float* __restrict__ x, const float* __restrict__ ef,
    const int* __restrict__ src, const int* __restrict__ dst,
    const float* __restrict__ W1, const float* __restrict__ b1,
    const float* __restrict__ W2, const float* __restrict__ b2,
    float* __restrict__ msum, float* __restrict__ cnt)
{
    const int e = blockIdx.x * blockDim.x + threadIdx.x;
    if (e >= NE) return;
    float efv[16];
    {
        const float4* p = reinterpret_cast<const float4*>(ef) + (size_t)e * 4;
        float4 a = p[0], b = p[1], c = p[2], d = p[3];
        efv[0]=a.x; efv[1]=a.y; efv[2]=a.z;  efv[3]=a.w;
        efv[4]=b.x; efv[5]=b.y; efv[6]=b.z;  efv[7]=b.w;
        efv[8]=c.x; efv[9]=c.y; efv[10]=c.z; efv[11]=c.w;
        efv[12]=d.x; efv[13]=d.y; efv[14]=d.z; efv[15]=d.w;
    }
    const int s = src[e];
    float xs[16];
    {
        const float4* p = reinterpret_cast<const float4*>(x) + (size_t)s * 4;
        float4 a = p[0], b = p[1], c = p[2], d = p[3];
        xs[0]=a.x; xs[1]=a.y; xs[2]=a.z;  xs[3]=a.w;
        xs[4]=b.x; xs[5]=b.y; xs[6]=b.z;  xs[7]=b.w;
        xs[8]=c.x; xs[9]=c.y; xs[10]=c.z; xs[11]=c.w;
        xs[12]=d.x; xs[13]=d.y; xs[14]=d.z; xs[15]=d.w;
    }
    float m[16];
    #pragma unroll
    for (int o = 0; o < 16; ++o) m[o] = 0.f;
    #pragma unroll
    for (int i = 0; i < 16; ++i) {
        const float xi = xs[i];
        #pragma unroll
        for (int o = 0; o < 16; ++o) m[o] = fmaf(xi, b2[i * 16 + o], m[o]);
    }
    for (int j = 0; j < HID; ++j) {
        float hj = b1[j];
        #pragma unroll
        for (int i = 0; i < 16; ++i) hj = fmaf(efv[i], W1[i * HID + j], hj);
        hj = fmaxf(hj, 0.f);
        const float* __restrict__ w2r = W2 + (size_t)j * 256;
        float t[16];
        #pragma unroll
        for (int o = 0; o < 16; ++o) t[o] = 0.f;
        #pragma unroll
        for (int i = 0; i < 16; ++i) {
            const float xi = xs[i];
            #pragma unroll
            for (int o = 0; o < 16; ++o) t[o] = fmaf(xi, w2r[i * 16 + o], t[o]);
        }
        #pragma unroll
        for (int o = 0; o < 16; ++o) m[o] = fmaf(hj, t[o], m[o]);
    }
    const int d = dst[e];
    float* mrow = msum + (size_t)d * 16;
    #pragma unroll
    for (int o = 0; o < 16; ++o) atomicAdd(mrow + o, m[o]);
    atomicAdd(cnt + d, 1.0f);
}

__global__ __launch_bounds__(256) void dgc_finalize(
    const float* __restrict__ msum, const float* __restrict__ cnt,
    const float* __restrict__ x, const float* __restrict__ bias,
    float* __restrict__ out)
{
    const int t = blockIdx.x * blockDim.x + threadIdx.x;
    if (t >= NN * FOUT) return;
    const int n = t >> 4;
    const int o = t & 15;
    const float c = cnt[n];
    const float v = (c > 0.f) ? (msum[t] / c) : x[t];
    out[t] = v + bias[o];
}

extern "C" void kernel_launch(void* const* d_in, const int* in_sizes, int n_in,
                              void* d_out, int out_size, void* d_ws, size_t ws_size,
                              hipStream_t stream) {
    const float* x    = (const float*)d_in[0];
    const float* ef   = (const float*)d_in[1];
    const int*   src  = (const int*)d_in[2];
    const int*   dst  = (const int*)d_in[3];
    const float* W1   = (const float*)d_in[4];
    const float* b1   = (const float*)d_in[5];
    const float* W2   = (const float*)d_in[6];
    const float* b2   = (const float*)d_in[7];
    const float* bias = (const float*)d_in[8];
    float* out = (float*)d_out;

    // CSR-path workspace layout
    float* msg  = (float*)d_ws;                       // NE*16 f32   (32 MB)
    int*   deg  = (int*)(msg + (size_t)NE * 16);      // NN
    int*   offs = deg + NN;                           // NN+1
    int*   pos  = offs + NN + 1;                      // NE
    int*   eidx = pos + NE;                           // NE
    const size_t needed = ((size_t)NE * 16 + NN + (NN + 1) + NE + NE) * 4;

    if (ws_size >= needed) {
        hipMemsetAsync(deg, 0, (size_t)NN * sizeof(int), stream);
        dgc_edge_csr<<<(NE + 255) / 256, 256, 0, stream>>>(
            x, ef, src, dst, W1, b1, W2, b2, msg, pos, deg);
        dgc_scan<<<1, 1024, 0, stream>>>(deg, offs);
        dgc_scatter<<<(NE + 255) / 256, 256, 0, stream>>>(dst, pos, offs, eidx);
        dgc_gather<<<(NN * FOUT + 255) / 256, 256, 0, stream>>>(
            msg, offs, eidx, x, bias, out);
    } else {
        float* msum = (float*)d_ws;                   // NN*16
        float* cnt  = msum + (size_t)NN * FOUT;       // NN
        hipMemsetAsync(d_ws, 0, ((size_t)NN * FOUT + NN) * sizeof(float), stream);
        dgc_edge_atomic<<<(NE + 255) / 256, 256, 0, stream>>>(
            x, ef, src, dst, W1, b1, W2, b2, msum, cnt);
        dgc_finalize<<<(NN * FOUT + 255) / 256, 256, 0, stream>>>(
            msum, cnt, x, bias, out);
    }
}